// Round 4
// baseline (362.791 us; speedup 1.0000x reference)
//
#include <hip/hip_runtime.h>
#include <math.h>

// Problem constants (from reference)
#define NB   64
#define CIN  3
#define PP   16      // pooled rows
#define QQ   12      // pooled cols
#define POOL_BLOCKS (NB * CIN * PP)   // 3072 strips
#define HEAD_BLOCKS (NB * 8)          // 512 (sample x 64-feature chunk)

typedef float f32x4 __attribute__((ext_vector_type(4)));

// ---------------------------------------------------------------------------
// Fused kernel.
// Blocks [0, 3072): 32x32 average pool of one contiguous strip
//   (sb = (n*3+c)*16+p, 12288 floats), then release-signal counter[n].
// Blocks [3072, 3584): head chunk (n, jc): spin-acquire counter[n]==48,
//   then threshold -> gate -> fold (algebraic) -> 64-feature GEMV slice.
//
// folded[c][i][j] = thr[c][i][j] * G[i][j],
//   G[i][j] = sum of gate[oh][ow] over windows covering padded pos (i+1,j+1)
//   gate[oh][ow] = sigmoid((10/27) * sum_{c,kh,kw} padthr[c][2oh+kh][2ow+kw])
// ---------------------------------------------------------------------------
__global__ __launch_bounds__(384)
void fused_kernel(const float* __restrict__ x,
                  const float* __restrict__ Wt,     // (576, 512) row-major
                  const float* __restrict__ bias,   // (512)
                  float* __restrict__ out,          // (N, 512)
                  float* __restrict__ pooled,       // (N*576)
                  int* __restrict__ counters)       // (N), zeroed per call
{
    const int bid = blockIdx.x;
    const int t   = threadIdx.x;

    if (bid < POOL_BLOCKS) {
        // ---------------- pool path ----------------
        const int col4 = t % 96;
        const int rg   = t / 96;
        const f32x4* base = reinterpret_cast<const f32x4*>(x) + (size_t)bid * 3072;

        float sum = 0.f;
#pragma unroll
        for (int r = rg; r < 32; r += 4) {
            f32x4 v = __builtin_nontemporal_load(&base[r * 96 + col4]);
            sum += (v.x + v.y) + (v.z + v.w);
        }

        __shared__ float part[384];
        part[t] = sum;
        __syncthreads();

        if (t < 96)
            part[t] = (part[t] + part[96 + t]) + (part[192 + t] + part[288 + t]);
        __syncthreads();

        if (t < QQ) {
            float tot = 0.f;
#pragma unroll
            for (int j = 0; j < 8; ++j)
                tot += part[t * 8 + j];
            pooled[bid * QQ + t] = tot * (1.0f / 1024.0f);
        }
        __syncthreads();   // drains this block's global stores (vmcnt(0) before barrier)

        if (t == 0) {
            __threadfence();   // device-scope release: push stores past local XCD L2
            __hip_atomic_fetch_add(&counters[bid / 48], 1,
                                   __ATOMIC_RELEASE, __HIP_MEMORY_SCOPE_AGENT);
        }
        return;
    }

    // ---------------- head path ----------------
    const int hb = bid - POOL_BLOCKS;
    const int n  = hb >> 3;          // sample 0..63
    const int jc = hb & 7;           // feature chunk 0..7

    if (t == 0) {
        while (__hip_atomic_load(&counters[n], __ATOMIC_ACQUIRE,
                                 __HIP_MEMORY_SCOPE_AGENT) < 48)
            __builtin_amdgcn_s_sleep(2);
    }
    __syncthreads();
    __threadfence();   // device-scope acquire: invalidate stale L1/L2 lines

    __shared__ float thr[576];       // [c*192 + i*12 + j]
    __shared__ float gate[48];       // [oh*6 + ow]
    __shared__ float f[576];         // folded, flattened
    __shared__ float partj[384];     // GEMV partials [kc*64 + l]

    for (int k = t; k < 576; k += 384) {
        float p = pooled[n * 576 + k];
        thr[k] = (p > 0.05f) ? p : 0.f;
    }
    __syncthreads();

    if (t < 48) {
        int oh = t / 6, ow = t - oh * 6;
        float S = 0.f;
#pragma unroll
        for (int c = 0; c < 3; ++c)
#pragma unroll
            for (int kh = 0; kh < 3; ++kh)
#pragma unroll
                for (int kw = 0; kw < 3; ++kw) {
                    int r  = oh * 2 + kh - 1;   // unpadded row
                    int sx = ow * 2 + kw - 1;   // unpadded col
                    if (r >= 0 && r < PP && sx >= 0 && sx < QQ)
                        S += thr[c * 192 + r * 12 + sx];
                }
        gate[t] = 1.f / (1.f + expf(-S * (10.0f / 27.0f)));
    }
    __syncthreads();

    for (int k = t; k < 576; k += 384) {
        int ij = k % 192;
        int i = ij / 12, j = ij - i * 12;
        int r = i + 1, sx = j + 1;             // padded coords
        float g = 0.f;
#pragma unroll
        for (int kh = 0; kh < 3; ++kh) {
            int oh2 = r - kh;
            if (oh2 < 0 || (oh2 & 1) || (oh2 >> 1) >= 8) continue;
            int oh = oh2 >> 1;
#pragma unroll
            for (int kw = 0; kw < 3; ++kw) {
                int ow2 = sx - kw;
                if (ow2 < 0 || (ow2 & 1) || (ow2 >> 1) >= 6) continue;
                g += gate[oh * 6 + (ow2 >> 1)];
            }
        }
        f[k] = thr[k] * g;
    }
    __syncthreads();

    // GEMV slice: 6-way k-split (96 each) x 64 features, coalesced W reads.
    const int l  = t & 63;
    const int kc = t >> 6;                     // 0..5
    const int j  = jc * 64 + l;
    const int k0 = kc * 96;
    const float* Wp = Wt + (size_t)k0 * 512 + j;
    float a0 = 0.f, a1 = 0.f, a2 = 0.f, a3 = 0.f;
#pragma unroll 6
    for (int kk = 0; kk < 96; kk += 4) {
        a0 = fmaf(f[k0 + kk + 0], Wp[(size_t)(kk + 0) * 512], a0);
        a1 = fmaf(f[k0 + kk + 1], Wp[(size_t)(kk + 1) * 512], a1);
        a2 = fmaf(f[k0 + kk + 2], Wp[(size_t)(kk + 2) * 512], a2);
        a3 = fmaf(f[k0 + kk + 3], Wp[(size_t)(kk + 3) * 512], a3);
    }
    partj[t] = (a0 + a1) + (a2 + a3);
    __syncthreads();

    if (t < 64) {
        float acc = bias[jc * 64 + t];
#pragma unroll
        for (int c = 0; c < 6; ++c)
            acc += partj[c * 64 + t];
        out[n * 512 + jc * 64 + t] = acc;
    }
}

// ---------------------------------------------------------------------------
extern "C" void kernel_launch(void* const* d_in, const int* in_sizes, int n_in,
                              void* d_out, int out_size, void* d_ws, size_t ws_size,
                              hipStream_t stream)
{
    const float* x    = (const float*)d_in[0];   // (64,3,512,384) f32
    const float* Wt   = (const float*)d_in[1];   // (576,512) f32
    const float* bias = (const float*)d_in[2];   // (512,) f32
    float* out = (float*)d_out;                  // (64,512) f32

    // ws layout: [0,256B) sample counters, [1KB, 1KB+147456B) pooled
    int*   counters = (int*)d_ws;
    float* pooled   = (float*)((char*)d_ws + 1024);

    hipMemsetAsync(counters, 0, NB * sizeof(int), stream);
    fused_kernel<<<POOL_BLOCKS + HEAD_BLOCKS, 384, 0, stream>>>(
        x, Wt, bias, out, pooled, counters);
}

// Round 5
// 74.175 us; speedup vs baseline: 4.8910x; 4.8910x over previous
//
#include <hip/hip_runtime.h>
#include <math.h>

// Problem constants (from reference)
#define NB   64
#define CIN  3
#define PP   16      // pooled rows
#define QQ   12      // pooled cols
#define POOL_BLOCKS (NB * CIN * PP)   // 3072 strips
#define HEAD_BLOCKS (NB * 8)          // 512 (sample x 64-feature chunk)

typedef float f32x4 __attribute__((ext_vector_type(4)));

// ---------------------------------------------------------------------------
// Fused kernel, zero-cache-maintenance producer/consumer handshake.
// Blocks [0, 3072): 32x32 average pool of one contiguous strip
//   (sb = (n*3+c)*16+p, 12288 floats). Pooled values are published with
//   relaxed AGENT-scope stores (write-through to coherence point), then
//   wave-0 drains vmcnt and bumps counter[n] (relaxed RMW). No buffer_wbl2.
// Blocks [3072, 3584): head chunk (n, jc): thread 0 spins on counter[n]==48
//   with RELAXED loads (no buffer_inv in loop!), then all threads read
//   pooled via relaxed AGENT loads (sc1 -> coherence point, never stale).
//
// folded[c][i][j] = thr[c][i][j] * G[i][j],
//   G[i][j] = sum of gate[oh][ow] over windows covering padded pos (i+1,j+1)
//   gate[oh][ow] = sigmoid((10/27) * sum_{c,kh,kw} padthr[c][2oh+kh][2ow+kw])
// ---------------------------------------------------------------------------
__global__ __launch_bounds__(384)
void fused_kernel(const float* __restrict__ x,
                  const float* __restrict__ Wt,     // (576, 512) row-major
                  const float* __restrict__ bias,   // (512)
                  float* __restrict__ out,          // (N, 512)
                  float* __restrict__ pooled,       // (N*576)
                  int* __restrict__ counters)       // (N), zeroed per call
{
    const int bid = blockIdx.x;
    const int t   = threadIdx.x;

    if (bid < POOL_BLOCKS) {
        // ---------------- pool path (identical math to R3) ----------------
        const int col4 = t % 96;
        const int rg   = t / 96;
        const f32x4* base = reinterpret_cast<const f32x4*>(x) + (size_t)bid * 3072;

        float sum = 0.f;
#pragma unroll
        for (int r = rg; r < 32; r += 4) {
            f32x4 v = base[r * 96 + col4];
            sum += (v.x + v.y) + (v.z + v.w);
        }

        __shared__ float part[384];
        part[t] = sum;
        __syncthreads();

        if (t < 96)
            part[t] = (part[t] + part[96 + t]) + (part[192 + t] + part[288 + t]);
        __syncthreads();

        if (t < QQ) {   // lanes 0..11 -- all in wave 0
            float tot = 0.f;
#pragma unroll
            for (int j = 0; j < 8; ++j)
                tot += part[t * 8 + j];
            __hip_atomic_store(&pooled[bid * QQ + t], tot * (1.0f / 1024.0f),
                               __ATOMIC_RELAXED, __HIP_MEMORY_SCOPE_AGENT);
        }
        // wave 0 issued the stores; drain THIS wave's vmcnt, then signal.
        if (t == 0) {
            asm volatile("s_waitcnt vmcnt(0)" ::: "memory");
            __hip_atomic_fetch_add(&counters[bid / 48], 1,
                                   __ATOMIC_RELAXED, __HIP_MEMORY_SCOPE_AGENT);
        }
        return;
    }

    // ---------------- head path ----------------
    const int hb = bid - POOL_BLOCKS;
    const int n  = hb >> 3;          // sample 0..63
    const int jc = hb & 7;           // feature chunk 0..7

    if (t == 0) {
        while (__hip_atomic_load(&counters[n], __ATOMIC_RELAXED,
                                 __HIP_MEMORY_SCOPE_AGENT) < 48)
            __builtin_amdgcn_s_sleep(8);
    }
    __syncthreads();   // no acquire fence needed: pooled reads below are sc1

    __shared__ float thr[576];       // [c*192 + i*12 + j]
    __shared__ float gate[48];       // [oh*6 + ow]
    __shared__ float f[576];         // folded, flattened
    __shared__ float partj[384];     // GEMV partials [kc*64 + l]

    for (int k = t; k < 576; k += 384) {
        float p = __hip_atomic_load(&pooled[n * 576 + k], __ATOMIC_RELAXED,
                                    __HIP_MEMORY_SCOPE_AGENT);
        thr[k] = (p > 0.05f) ? p : 0.f;
    }
    __syncthreads();

    if (t < 48) {
        int oh = t / 6, ow = t - oh * 6;
        float S = 0.f;
#pragma unroll
        for (int c = 0; c < 3; ++c)
#pragma unroll
            for (int kh = 0; kh < 3; ++kh)
#pragma unroll
                for (int kw = 0; kw < 3; ++kw) {
                    int r  = oh * 2 + kh - 1;   // unpadded row
                    int sx = ow * 2 + kw - 1;   // unpadded col
                    if (r >= 0 && r < PP && sx >= 0 && sx < QQ)
                        S += thr[c * 192 + r * 12 + sx];
                }
        gate[t] = 1.f / (1.f + expf(-S * (10.0f / 27.0f)));
    }
    __syncthreads();

    for (int k = t; k < 576; k += 384) {
        int ij = k % 192;
        int i = ij / 12, j = ij - i * 12;
        int r = i + 1, sx = j + 1;             // padded coords
        float g = 0.f;
#pragma unroll
        for (int kh = 0; kh < 3; ++kh) {
            int oh2 = r - kh;
            if (oh2 < 0 || (oh2 & 1) || (oh2 >> 1) >= 8) continue;
            int oh = oh2 >> 1;
#pragma unroll
            for (int kw = 0; kw < 3; ++kw) {
                int ow2 = sx - kw;
                if (ow2 < 0 || (ow2 & 1) || (ow2 >> 1) >= 6) continue;
                g += gate[oh * 6 + (ow2 >> 1)];
            }
        }
        f[k] = thr[k] * g;
    }
    __syncthreads();

    // GEMV slice: 6-way k-split (96 each) x 64 features, coalesced W reads.
    const int l  = t & 63;
    const int kc = t >> 6;                     // 0..5
    const int j  = jc * 64 + l;
    const int k0 = kc * 96;
    const float* Wp = Wt + (size_t)k0 * 512 + j;
    float a0 = 0.f, a1 = 0.f, a2 = 0.f, a3 = 0.f;
#pragma unroll 6
    for (int kk = 0; kk < 96; kk += 4) {
        a0 = fmaf(f[k0 + kk + 0], Wp[(size_t)(kk + 0) * 512], a0);
        a1 = fmaf(f[k0 + kk + 1], Wp[(size_t)(kk + 1) * 512], a1);
        a2 = fmaf(f[k0 + kk + 2], Wp[(size_t)(kk + 2) * 512], a2);
        a3 = fmaf(f[k0 + kk + 3], Wp[(size_t)(kk + 3) * 512], a3);
    }
    partj[t] = (a0 + a1) + (a2 + a3);
    __syncthreads();

    if (t < 64) {
        float acc = bias[jc * 64 + t];
#pragma unroll
        for (int c = 0; c < 6; ++c)
            acc += partj[c * 64 + t];
        out[n * 512 + jc * 64 + t] = acc;
    }
}

// ---------------------------------------------------------------------------
extern "C" void kernel_launch(void* const* d_in, const int* in_sizes, int n_in,
                              void* d_out, int out_size, void* d_ws, size_t ws_size,
                              hipStream_t stream)
{
    const float* x    = (const float*)d_in[0];   // (64,3,512,384) f32
    const float* Wt   = (const float*)d_in[1];   // (576,512) f32
    const float* bias = (const float*)d_in[2];   // (512,) f32
    float* out = (float*)d_out;                  // (64,512) f32

    // ws layout: [0,256B) sample counters, [1KB, 1KB+147456B) pooled
    int*   counters = (int*)d_ws;
    float* pooled   = (float*)((char*)d_ws + 1024);

    hipMemsetAsync(counters, 0, NB * sizeof(int), stream);
    fused_kernel<<<POOL_BLOCKS + HEAD_BLOCKS, 384, 0, stream>>>(
        x, Wt, bias, out, pooled, counters);
}

// Round 6
// 53.730 us; speedup vs baseline: 6.7522x; 1.3805x over previous
//
#include <hip/hip_runtime.h>
#include <math.h>

// Problem constants (from reference)
#define NB   64
#define CIN  3
#define PP   16      // pooled rows
#define QQ   12      // pooled cols
#define POOL_BLOCKS (NB * CIN * PP)   // 3072 strips (48 per sample)
#define CTR_STRIDE  32                // ints -> 128 B per sample counter line

typedef float f32x4 __attribute__((ext_vector_type(4)));

// ---------------------------------------------------------------------------
// Single-grid fused kernel, "last finishers do the head".
// Every block pools one contiguous strip (bid = (n*3+c)*16+p, 12288 floats),
// publishes 12 pooled values with relaxed AGENT sc1 stores (write-through,
// no cache maintenance), drains vmcnt in wave 0, then fetch_add(counter[n]).
// The blocks that receive ranks 44..47 each compute one 128-feature quarter
// of sample n's head (ranks 44..46 briefly spin until count==48 -- bounded,
// <=3 single-thread spinners on a private 128B line). Protocol identical to
// the R5-validated one; no standing spinner blocks, no fences, no inv/wb.
//
// folded[c][i][j] = thr[c][i][j] * G[i][j],
//   G[i][j] = sum of gate[oh][ow] over windows covering padded pos (i+1,j+1)
//   gate[oh][ow] = sigmoid((10/27) * sum_{c,kh,kw} padthr[c][2oh+kh][2ow+kw])
// ---------------------------------------------------------------------------
__global__ __launch_bounds__(384)
void fused_kernel(const float* __restrict__ x,
                  const float* __restrict__ Wt,     // (576, 512) row-major
                  const float* __restrict__ bias,   // (512)
                  float* __restrict__ out,          // (N, 512)
                  float* __restrict__ pooled,       // (N*576)
                  int* __restrict__ counters)       // (N*CTR_STRIDE), zeroed
{
    const int bid = blockIdx.x;      // 0..3071
    const int t   = threadIdx.x;
    const int n   = bid / 48;        // sample

    __shared__ float part[384];
    __shared__ float thr[576];       // [c*192 + i*12 + j]
    __shared__ float gate[48];       // [oh*6 + ow]
    __shared__ float f[576];         // folded, flattened
    __shared__ int   rank_s;

    // ---------------- pool: one 32x32-block strip ----------------
    {
        const int col4 = t % 96;
        const int rg   = t / 96;
        const f32x4* base = reinterpret_cast<const f32x4*>(x) + (size_t)bid * 3072;

        float sum = 0.f;
#pragma unroll
        for (int r = rg; r < 32; r += 4) {
            f32x4 v = base[r * 96 + col4];
            sum += (v.x + v.y) + (v.z + v.w);
        }
        part[t] = sum;
        __syncthreads();

        if (t < 96)
            part[t] = (part[t] + part[96 + t]) + (part[192 + t] + part[288 + t]);
        __syncthreads();

        if (t < QQ) {   // lanes 0..11, all in wave 0
            float tot = 0.f;
#pragma unroll
            for (int j = 0; j < 8; ++j)
                tot += part[t * 8 + j];
            __hip_atomic_store(&pooled[bid * QQ + t], tot * (1.0f / 1024.0f),
                               __ATOMIC_RELAXED, __HIP_MEMORY_SCOPE_AGENT);
        }
    }

    // wave 0 issued the sc1 stores; drain this wave's vmcnt, then signal.
    if (t == 0) {
        asm volatile("s_waitcnt vmcnt(0)" ::: "memory");
        rank_s = __hip_atomic_fetch_add(&counters[n * CTR_STRIDE], 1,
                                        __ATOMIC_RELAXED, __HIP_MEMORY_SCOPE_AGENT);
    }
    __syncthreads();
    const int rank = rank_s;
    if (rank < 44) return;           // uniform per block

    const int jq = rank - 44;        // feature quarter 0..3

    // ranks 44..46: bounded spin until all 48 strips of sample n published.
    if (t == 0 && rank < 47) {
        while (__hip_atomic_load(&counters[n * CTR_STRIDE], __ATOMIC_RELAXED,
                                 __HIP_MEMORY_SCOPE_AGENT) < 48)
            __builtin_amdgcn_s_sleep(1);
    }
    __syncthreads();

    // ---------------- head quarter: thr -> gate -> f -> GEMV(128 feats) ---
    for (int k = t; k < 576; k += 384) {
        float p = __hip_atomic_load(&pooled[n * 576 + k], __ATOMIC_RELAXED,
                                    __HIP_MEMORY_SCOPE_AGENT);
        thr[k] = (p > 0.05f) ? p : 0.f;
    }
    __syncthreads();

    if (t < 48) {
        int oh = t / 6, ow = t - oh * 6;
        float S = 0.f;
#pragma unroll
        for (int c = 0; c < 3; ++c)
#pragma unroll
            for (int kh = 0; kh < 3; ++kh)
#pragma unroll
                for (int kw = 0; kw < 3; ++kw) {
                    int r  = oh * 2 + kh - 1;   // unpadded row
                    int sx = ow * 2 + kw - 1;   // unpadded col
                    if (r >= 0 && r < PP && sx >= 0 && sx < QQ)
                        S += thr[c * 192 + r * 12 + sx];
                }
        gate[t] = 1.f / (1.f + expf(-S * (10.0f / 27.0f)));
    }
    __syncthreads();

    for (int k = t; k < 576; k += 384) {
        int ij = k % 192;
        int i = ij / 12, j = ij - i * 12;
        int r = i + 1, sx = j + 1;             // padded coords
        float g = 0.f;
#pragma unroll
        for (int kh = 0; kh < 3; ++kh) {
            int oh2 = r - kh;
            if (oh2 < 0 || (oh2 & 1) || (oh2 >> 1) >= 8) continue;
            int oh = oh2 >> 1;
#pragma unroll
            for (int kw = 0; kw < 3; ++kw) {
                int ow2 = sx - kw;
                if (ow2 < 0 || (ow2 & 1) || (ow2 >> 1) >= 6) continue;
                g += gate[oh * 6 + (ow2 >> 1)];
            }
        }
        f[k] = thr[k] * g;
    }
    __syncthreads();

    // GEMV slice: 3 k-chunks (192 each) x 128 features of quarter jq.
    const int l  = t & 127;                    // feature within quarter
    const int kc = t >> 7;                     // 0..2
    const int j  = jq * 128 + l;
    const int k0 = kc * 192;
    const float* Wp = Wt + (size_t)k0 * 512 + j;
    float a0 = 0.f, a1 = 0.f, a2 = 0.f, a3 = 0.f;
#pragma unroll 8
    for (int kk = 0; kk < 192; kk += 4) {
        a0 = fmaf(f[k0 + kk + 0], Wp[(size_t)(kk + 0) * 512], a0);
        a1 = fmaf(f[k0 + kk + 1], Wp[(size_t)(kk + 1) * 512], a1);
        a2 = fmaf(f[k0 + kk + 2], Wp[(size_t)(kk + 2) * 512], a2);
        a3 = fmaf(f[k0 + kk + 3], Wp[(size_t)(kk + 3) * 512], a3);
    }
    __syncthreads();                 // part[] reuse below
    part[t] = (a0 + a1) + (a2 + a3);
    __syncthreads();

    if (t < 128) {
        out[n * 512 + j] = bias[j] + part[t] + part[128 + t] + part[256 + t];
    }
}

// ---------------------------------------------------------------------------
extern "C" void kernel_launch(void* const* d_in, const int* in_sizes, int n_in,
                              void* d_out, int out_size, void* d_ws, size_t ws_size,
                              hipStream_t stream)
{
    const float* x    = (const float*)d_in[0];   // (64,3,512,384) f32
    const float* Wt   = (const float*)d_in[1];   // (576,512) f32
    const float* bias = (const float*)d_in[2];   // (512,) f32
    float* out = (float*)d_out;                  // (64,512) f32

    // ws layout: [0, 8KB) padded counters, [8KB, 8KB+147456B) pooled
    int*   counters = (int*)d_ws;
    float* pooled   = (float*)((char*)d_ws + 8192);

    hipMemsetAsync(counters, 0, NB * CTR_STRIDE * sizeof(int), stream);
    fused_kernel<<<POOL_BLOCKS, 384, 0, stream>>>(
        x, Wt, bias, out, pooled, counters);
}

// Round 7
// 33.795 us; speedup vs baseline: 10.7351x; 1.5899x over previous
//
#include <hip/hip_runtime.h>
#include <math.h>

// Problem constants (from reference)
#define NB   64
#define CIN  3
#define PP   16      // pooled rows
#define QQ   12      // pooled cols

typedef float f32x4 __attribute__((ext_vector_type(4)));

// ---------------------------------------------------------------------------
// Kernel 1: 32x32 average pooling, one WAVE per pooled output.
// 36864 outputs -> 9216 blocks x 256 threads (4 waves/block).
// Output o = strip*12 + q, strip = (n*3+c)*16+p (contiguous 12288-float chunk).
// Lane l reads 4 float4: rows (l>>3)+8i of the strip, f4-col q*8+(l&7)
//   -> per load instruction: 8 fully-used 128 B segments (stride 1536 B).
// Register sum -> 6-step __shfl_xor wave reduce -> lane 0 stores.
// No LDS, no __syncthreads: waves retire independently (minimal block tail).
// ---------------------------------------------------------------------------
__global__ __launch_bounds__(256)
void pool_kernel(const float* __restrict__ x, float* __restrict__ pooled)
{
    const int t  = threadIdx.x;
    const int o  = blockIdx.x * 4 + (t >> 6);   // global wave id = output id
    const int l  = t & 63;
    const int strip = o / QQ;
    const int q     = o - strip * QQ;

    const f32x4* base = reinterpret_cast<const f32x4*>(x) + (size_t)strip * 3072
                      + q * 8 + (l & 7);
    const int r0 = l >> 3;                      // 0..7

    f32x4 v0 = base[(r0 +  0) * 96];
    f32x4 v1 = base[(r0 +  8) * 96];
    f32x4 v2 = base[(r0 + 16) * 96];
    f32x4 v3 = base[(r0 + 24) * 96];

    float s = ((v0.x + v0.y) + (v0.z + v0.w))
            + ((v1.x + v1.y) + (v1.z + v1.w))
            + ((v2.x + v2.y) + (v2.z + v2.w))
            + ((v3.x + v3.y) + (v3.z + v3.w));

#pragma unroll
    for (int off = 32; off >= 1; off >>= 1)
        s += __shfl_xor(s, off, 64);

    if (l == 0)
        pooled[o] = s * (1.0f / 1024.0f);
}

// ---------------------------------------------------------------------------
// Kernel 2 (R3-verified): threshold -> gate -> fold (algebraic) -> projection.
// grid = 64 samples x 8 feature-chunks = 512 blocks; block = 512 threads.
// Thread t: l = t&63 -> feature j = jc*64+l; kc = t>>6 -> k in [kc*72,kc*72+72).
//
// folded[c][i][j] = thr[c][i][j] * G[i][j],
//   G[i][j] = sum of gate[oh][ow] over windows covering padded pos (i+1,j+1)
//   gate[oh][ow] = sigmoid((10/27) * sum_{c,kh,kw} padthr[c][2oh+kh][2ow+kw])
// ---------------------------------------------------------------------------
__global__ __launch_bounds__(512)
void head_kernel(const float* __restrict__ pooled,
                 const float* __restrict__ Wt,     // (576, 512) row-major
                 const float* __restrict__ bias,   // (512)
                 float* __restrict__ out)          // (N, 512)
{
    const int blk = blockIdx.x;      // 0..511
    const int n   = blk >> 3;        // sample 0..63
    const int jc  = blk & 7;         // feature chunk 0..7
    const int t   = threadIdx.x;
    const int l   = t & 63;          // lane -> feature jc*64+l
    const int kc  = t >> 6;          // k-chunk 0..7

    __shared__ float thr[576];       // [c*192 + i*12 + j]
    __shared__ float gate[48];       // [oh*6 + ow]
    __shared__ float f[576];         // folded, flattened
    __shared__ float part[512];      // projection partials [kc*64 + l]

    for (int k = t; k < 576; k += 512) {
        float p = pooled[n * 576 + k];
        thr[k] = (p > 0.05f) ? p : 0.f;
    }
    __syncthreads();

    if (t < 48) {
        int oh = t / 6, ow = t - oh * 6;
        float S = 0.f;
#pragma unroll
        for (int c = 0; c < 3; ++c)
#pragma unroll
            for (int kh = 0; kh < 3; ++kh)
#pragma unroll
                for (int kw = 0; kw < 3; ++kw) {
                    int r  = oh * 2 + kh - 1;   // unpadded row
                    int sx = ow * 2 + kw - 1;   // unpadded col
                    if (r >= 0 && r < PP && sx >= 0 && sx < QQ)
                        S += thr[c * 192 + r * 12 + sx];
                }
        gate[t] = 1.f / (1.f + expf(-S * (10.0f / 27.0f)));
    }
    __syncthreads();

    for (int k = t; k < 576; k += 512) {
        int ij = k % 192;
        int i = ij / 12, j = ij - i * 12;
        int r = i + 1, sx = j + 1;             // padded coords
        float g = 0.f;
#pragma unroll
        for (int kh = 0; kh < 3; ++kh) {
            int oh2 = r - kh;
            if (oh2 < 0 || (oh2 & 1) || (oh2 >> 1) >= 8) continue;
            int oh = oh2 >> 1;
#pragma unroll
            for (int kw = 0; kw < 3; ++kw) {
                int ow2 = sx - kw;
                if (ow2 < 0 || (ow2 & 1) || (ow2 >> 1) >= 6) continue;
                g += gate[oh * 6 + (ow2 >> 1)];
            }
        }
        f[k] = thr[k] * g;
    }
    __syncthreads();

    // projection partial: part[kc*64+l] = sum_{k in chunk} f[k] * Wt[k*512+j]
    const int j  = jc * 64 + l;
    const int k0 = kc * 72;
    const float* Wp = Wt + (size_t)k0 * 512 + j;
    float a0 = 0.f, a1 = 0.f, a2 = 0.f, a3 = 0.f;
#pragma unroll 6
    for (int kk = 0; kk < 72; kk += 4) {
        a0 = fmaf(f[k0 + kk + 0], Wp[(size_t)(kk + 0) * 512], a0);
        a1 = fmaf(f[k0 + kk + 1], Wp[(size_t)(kk + 1) * 512], a1);
        a2 = fmaf(f[k0 + kk + 2], Wp[(size_t)(kk + 2) * 512], a2);
        a3 = fmaf(f[k0 + kk + 3], Wp[(size_t)(kk + 3) * 512], a3);
    }
    part[t] = (a0 + a1) + (a2 + a3);
    __syncthreads();

    // reduce 8 k-chunks per feature
    if (t < 64) {
        float acc = bias[j];
#pragma unroll
        for (int c = 0; c < 8; ++c)
            acc += part[c * 64 + t];
        out[n * 512 + j] = acc;
    }
}

// ---------------------------------------------------------------------------
extern "C" void kernel_launch(void* const* d_in, const int* in_sizes, int n_in,
                              void* d_out, int out_size, void* d_ws, size_t ws_size,
                              hipStream_t stream)
{
    const float* x    = (const float*)d_in[0];   // (64,3,512,384) f32
    const float* Wt   = (const float*)d_in[1];   // (576,512) f32
    const float* bias = (const float*)d_in[2];   // (512,) f32
    float* out = (float*)d_out;                  // (64,512) f32
    float* pooled = (float*)d_ws;                // 64*3*16*12 = 36864 floats

    pool_kernel<<<(NB * CIN * PP * QQ) / 4, 256, 0, stream>>>(x, pooled);
    head_kernel<<<NB * 8, 512, 0, stream>>>(pooled, Wt, bias, out);
}